// Round 6
// baseline (763.210 us; speedup 1.0000x reference)
//
#include <hip/hip_runtime.h>
#include <hip/hip_bf16.h>

typedef __hip_bfloat16 bf16;
typedef __attribute__((ext_vector_type(8))) short short8;
typedef __attribute__((ext_vector_type(4))) short short4v;
typedef __attribute__((ext_vector_type(4))) float f32x4;

#define MFMA16(a, b, c) __builtin_amdgcn_mfma_f32_16x16x32_bf16((a), (b), (c), 0, 0, 0)

static __device__ __forceinline__ void gload_lds16(const bf16* g, bf16* l) {
  __builtin_amdgcn_global_load_lds((const __attribute__((address_space(1))) unsigned int*)g,
                                   (__attribute__((address_space(3))) unsigned int*)l,
                                   16, 0, 0);
}

// ---------------- cast x: fp32 -> bf16 ----------------
__global__ __launch_bounds__(256) void castx_kernel(const float* __restrict__ x,
                                                    bf16* __restrict__ xb, int n) {
  int i = (blockIdx.x * 256 + threadIdx.x) * 8;
  if (i >= n) return;
  float4 v0 = *(const float4*)(x + i);
  float4 v1 = *(const float4*)(x + i + 4);
  bf16 tmp[8];
  tmp[0] = __float2bfloat16(v0.x); tmp[1] = __float2bfloat16(v0.y);
  tmp[2] = __float2bfloat16(v0.z); tmp[3] = __float2bfloat16(v0.w);
  tmp[4] = __float2bfloat16(v1.x); tmp[5] = __float2bfloat16(v1.y);
  tmp[6] = __float2bfloat16(v1.z); tmp[7] = __float2bfloat16(v1.w);
  *(short8*)(xb + i) = *(short8*)tmp;
}

// ---------------- transpose+cast weight: W[K][N] fp32 -> WT[N][K] bf16 ----------------
__global__ __launch_bounds__(256) void tw_kernel(const float* __restrict__ W,
                                                 bf16* __restrict__ WT) {
  __shared__ bf16 tile[64][65];
  int b = blockIdx.x;
  int tk = (b >> 6) * 64;
  int tn = (b & 63) * 64;
  int t = threadIdx.x;
  int c = t & 63, r0 = t >> 6;
#pragma unroll
  for (int i = 0; i < 16; ++i) {
    int r = i * 4 + r0;
    tile[c][r] = __float2bfloat16(W[(size_t)(tk + r) * 4096 + tn + c]);
  }
  __syncthreads();
#pragma unroll
  for (int i = 0; i < 16; ++i) {
    int r = i * 4 + r0;
    WT[(size_t)(tn + r) * 4096 + tk + c] = tile[r][c];
  }
}

// ---------------- GEMM v3: C = A[M][K](bf16) * Bt[N][K]^T, fused epilogues ----------------
// EPI: 1 = RoPE+scale (Q), 2 = RoPE (K), 3 = transposed store Vt[col][row], 4 = fp32 store.
// BM=128 BN=256 BK=64, 512 thr = 8 waves (2m x 4n), wave tile 64x64.
// A: register-direct from global, double-buffered across K-tiles (no LDS round-trip).
// B: LDS double buffer 2x32KB, gload_lds, 3-bit XOR swizzle (granule ^= row&7).
// 2 barriers/K-tile, counted vmcnt(12), setprio around merged 32-MFMA cluster.
// XCD-chunked block swizzle: each XCD owns 2 consecutive bm rows (A L2-resident).
template <int EPI>
__global__ __launch_bounds__(512, 2) void gemm3(const bf16* __restrict__ A,
                                                const bf16* __restrict__ Bt,
                                                void* __restrict__ Cv,
                                                int M, int N, int K,
                                                const float* __restrict__ fcos,
                                                const float* __restrict__ fsin) {
  __shared__ bf16 Bs[2][256 * 64];
  const int NB = N >> 8;
  int g = blockIdx.x;
  int nwg = (M >> 7) * NB;                    // 256 for our shapes
  int wid = (g & 7) * (nwg >> 3) + (g >> 3);  // XCD-chunked (nwg % 8 == 0)
  int bm = wid / NB, bn = wid % NB;
  int t = threadIdx.x, lane = t & 63, w = t >> 6;
  int wm = w >> 2, wn = w & 3;
  int lr = lane & 15, lg = lane >> 4;
  f32x4 acc[4][4] = {};

  const bf16* Bb = Bt + (size_t)bn * 256 * K;
  int srow = t >> 3;                 // 0..63: row within 64-row slab being staged
  int sg = (t & 7) ^ (srow & 7);     // inverse-swizzled source granule
  int NK = K >> 6;

  // per-m-fragment A row pointers (lane lr picks row, lg picks k-subchunk)
  const bf16* arow[4];
#pragma unroll
  for (int m = 0; m < 4; ++m)
    arow[m] = A + (size_t)(bm * 128 + wm * 64 + m * 16 + lr) * K + lg * 8;

#define GSTAGE(buf, kt)                                                    \
  do {                                                                     \
    const bf16* gb_ = Bb + (size_t)(kt) * 64;                              \
    bf16* lb_ = Bs[buf];                                                   \
    _Pragma("unroll") for (int i = 0; i < 4; ++i)                          \
      gload_lds16(gb_ + (size_t)(i * 64 + srow) * K + sg * 8,              \
                  lb_ + (i * 512 + w * 64) * 8);                           \
  } while (0)

  // B-fragment read: row = wn*64+nf*16+lr, granule = row*8 + ((kc*4+lg)^(lr&7))
#define BFRAG(lb, nf, kc) \
  (*(const short8*)((lb) + (((wn * 64 + (nf)*16 + lr) * 8 + (((kc)*4 + lg) ^ (lr & 7))) * 8)))

  short8 a0[4][2], a1[4][2];
#pragma unroll
  for (int m = 0; m < 4; ++m)
#pragma unroll
    for (int kc = 0; kc < 2; ++kc)
      a0[m][kc] = *(const short8*)(arow[m] + kc * 32);
  GSTAGE(0, 0);

  for (int kt = 0; kt < NK; kt += 2) {
    // ======== even sub-iter: compute kt with a0, Bs[0] ========
    if (kt + 1 < NK) {
#pragma unroll
      for (int m = 0; m < 4; ++m)
#pragma unroll
        for (int kc = 0; kc < 2; ++kc)
          a1[m][kc] = *(const short8*)(arow[m] + (kt + 1) * 64 + kc * 32);
      GSTAGE(1, kt + 1);
      asm volatile("s_waitcnt vmcnt(12)" ::: "memory");
    } else {
      asm volatile("s_waitcnt vmcnt(0)" ::: "memory");
    }
    __builtin_amdgcn_s_barrier();
    {
      const bf16* lb = Bs[0];
      short8 b[4][2];
#pragma unroll
      for (int nf = 0; nf < 4; ++nf)
#pragma unroll
        for (int kc = 0; kc < 2; ++kc)
          b[nf][kc] = BFRAG(lb, nf, kc);
      __builtin_amdgcn_s_setprio(1);
#pragma unroll
      for (int m = 0; m < 4; ++m)
#pragma unroll
        for (int nf = 0; nf < 4; ++nf)
#pragma unroll
          for (int kc = 0; kc < 2; ++kc)
            acc[m][nf] = MFMA16(a0[m][kc], b[nf][kc], acc[m][nf]);
      __builtin_amdgcn_s_setprio(0);
    }
    __builtin_amdgcn_s_barrier();

    // ======== odd sub-iter: compute kt+1 with a1, Bs[1] ========
    if (kt + 2 < NK) {
#pragma unroll
      for (int m = 0; m < 4; ++m)
#pragma unroll
        for (int kc = 0; kc < 2; ++kc)
          a0[m][kc] = *(const short8*)(arow[m] + (kt + 2) * 64 + kc * 32);
      GSTAGE(0, kt + 2);
      asm volatile("s_waitcnt vmcnt(12)" ::: "memory");
    } else {
      asm volatile("s_waitcnt vmcnt(0)" ::: "memory");
    }
    __builtin_amdgcn_s_barrier();
    {
      const bf16* lb = Bs[1];
      short8 b[4][2];
#pragma unroll
      for (int nf = 0; nf < 4; ++nf)
#pragma unroll
        for (int kc = 0; kc < 2; ++kc)
          b[nf][kc] = BFRAG(lb, nf, kc);
      __builtin_amdgcn_s_setprio(1);
#pragma unroll
      for (int m = 0; m < 4; ++m)
#pragma unroll
        for (int nf = 0; nf < 4; ++nf)
#pragma unroll
          for (int kc = 0; kc < 2; ++kc)
            acc[m][nf] = MFMA16(a1[m][kc], b[nf][kc], acc[m][nf]);
      __builtin_amdgcn_s_setprio(0);
    }
    __builtin_amdgcn_s_barrier();
  }
#undef GSTAGE
#undef BFRAG

#pragma unroll
  for (int m = 0; m < 4; ++m)
#pragma unroll
    for (int nf = 0; nf < 4; ++nf) {
      int col = bn * 256 + wn * 64 + nf * 16 + lr;
      int row0 = bm * 128 + wm * 64 + m * 16 + lg * 4;
      if constexpr (EPI == 1 || EPI == 2) {
        const float qs = (EPI == 1) ? 0.08838834764831845f : 1.0f;
        int ip = (col >> 1) & 63;
        float sgn = (col & 1) ? 1.0f : -1.0f;
#pragma unroll
        for (int r = 0; r < 4; ++r) {
          int row = row0 + r;
          float mine = acc[m][nf][r];
          float oth = __shfl_xor(mine, 1);
          float cv = fcos[row * 64 + ip];
          float sv = fsin[row * 64 + ip];
          float v = (mine * cv + sgn * oth * sv) * qs;
          ((bf16*)Cv)[(size_t)row * N + col] = __float2bfloat16(v);
        }
      } else if constexpr (EPI == 3) {
        bf16 tmp[4];
#pragma unroll
        for (int r = 0; r < 4; ++r) tmp[r] = __float2bfloat16(acc[m][nf][r]);
        *(short4v*)((bf16*)Cv + (size_t)col * M + row0) = *(short4v*)tmp;
      } else {
#pragma unroll
        for (int r = 0; r < 4; ++r) {
          int row = row0 + r;
          ((float*)Cv)[(size_t)row * N + col] = acc[m][nf][r];
        }
      }
    }
}

// ---------------- Flash attention v3 (unchanged from r5) ----------------
__global__ __launch_bounds__(512, 2) void attn_fwd(const bf16* __restrict__ Q,
                                                   const bf16* __restrict__ K,
                                                   const bf16* __restrict__ Vt,
                                                   bf16* __restrict__ O) {
  __shared__ bf16 Kbuf[2][64 * 128];
  __shared__ bf16 Vbuf[2][128 * 64];
  __shared__ char Ps_all[8][2][2048];
  const int S = 2048, D = 4096, HD = 128, NT = 32;
  int g = blockIdx.y * 8 + blockIdx.x;
  int wid = (g & 7) * 32 + (g >> 3);
  int h = wid >> 3, qb = wid & 7;
  int tid = threadIdx.x, lane = tid & 63, w = tid >> 6;
  int lr = lane & 15, lg = lane >> 4;
  int q0 = qb * 256 + w * 32;
  int swz = (lr & 7) << 4;

  const bf16* Kh = K + h * HD;
  const bf16* Vh = Vt + (size_t)h * HD * S;

  short8 aq[2][4];
#pragma unroll
  for (int u = 0; u < 2; ++u)
#pragma unroll
    for (int c = 0; c < 4; ++c)
      aq[u][c] = *(const short8*)(Q + (size_t)(q0 + u * 16 + lr) * D + h * HD + c * 32 + lg * 8);

  int kr = lane >> 4, ksl = lane & 15;
  int vr = lane >> 3, vsl = lane & 7;

  f32x4 accO[2][8] = {};
  float lsum[2] = {0.f, 0.f};

#define STAGE(b, ttile)                                                            \
  do {                                                                             \
    int kv0_ = (ttile) * 64;                                                       \
    _Pragma("unroll") for (int ii = 0; ii < 2; ++ii) {                             \
      int row = w * 8 + ii * 4 + kr;                                               \
      gload_lds16(Kh + (size_t)(kv0_ + row) * D + ((ksl ^ (row & 7)) << 3),        \
                  &Kbuf[b][(w * 8 + ii * 4) * 128]);                               \
    }                                                                              \
    _Pragma("unroll") for (int ii = 0; ii < 2; ++ii) {                             \
      int row = w * 16 + ii * 8 + vr;                                              \
      gload_lds16(Vh + (size_t)row * S + kv0_ + ((vsl ^ (row & 7)) << 3),          \
                  &Vbuf[b][(w * 16 + ii * 8) * 64]);                               \
    }                                                                              \
  } while (0)

  int cur = 0;
  STAGE(0, 0);
  for (int tt = 0; tt < NT; ++tt) {
    if (tt + 1 < NT) {
      STAGE(cur ^ 1, tt + 1);
      asm volatile("s_waitcnt vmcnt(4)" ::: "memory");
    } else {
      asm volatile("s_waitcnt vmcnt(0)" ::: "memory");
    }
    __builtin_amdgcn_s_barrier();
    const bf16* Kb_ = Kbuf[cur];
    const bf16* Vb_ = Vbuf[cur];

    f32x4 sf[2][4] = {};
#pragma unroll
    for (int j = 0; j < 4; ++j)
#pragma unroll
      for (int c = 0; c < 4; ++c) {
        short8 kf = *(const short8*)(Kb_ + (j * 16 + lr) * 128 +
                                     (((c * 4 + lg) ^ (lr & 7)) << 3));
        sf[0][j] = MFMA16(kf, aq[0][c], sf[0][j]);
        sf[1][j] = MFMA16(kf, aq[1][c], sf[1][j]);
      }
#pragma unroll
    for (int u = 0; u < 2; ++u) {
      char* Ps = Ps_all[w][u];
#pragma unroll
      for (int j = 0; j < 4; ++j) {
        float p0 = __expf(sf[u][j][0]);
        float p1 = __expf(sf[u][j][1]);
        float p2 = __expf(sf[u][j][2]);
        float p3 = __expf(sf[u][j][3]);
        lsum[u] += (p0 + p1) + (p2 + p3);
        bf16 pk[4] = {__float2bfloat16(p0), __float2bfloat16(p1),
                      __float2bfloat16(p2), __float2bfloat16(p3)};
        *(short4v*)(Ps + lr * 128 + ((j * 32 + lg * 8) ^ swz)) = *(short4v*)pk;
      }
    }
#pragma unroll
    for (int t2 = 0; t2 < 2; ++t2) {
      short8 pa0 = *(const short8*)(Ps_all[w][0] + lr * 128 + ((t2 * 64 + lg * 16) ^ swz));
      short8 pa1 = *(const short8*)(Ps_all[w][1] + lr * 128 + ((t2 * 64 + lg * 16) ^ swz));
#pragma unroll
      for (int n = 0; n < 8; ++n) {
        short8 bv = *(const short8*)(Vb_ + (n * 16 + lr) * 64 +
                                     (((t2 * 4 + lg) ^ (lr & 7)) << 3));
        accO[0][n] = MFMA16(pa0, bv, accO[0][n]);
        accO[1][n] = MFMA16(pa1, bv, accO[1][n]);
      }
    }
    __builtin_amdgcn_s_barrier();
    cur ^= 1;
  }
#undef STAGE

#pragma unroll
  for (int u = 0; u < 2; ++u) {
    float ls = lsum[u];
    ls += __shfl_xor(ls, 16);
    ls += __shfl_xor(ls, 32);
    float rs[4];
#pragma unroll
    for (int r = 0; r < 4; ++r)
      rs[r] = 1.f / __shfl(ls, lg * 4 + r);
#pragma unroll
    for (int n = 0; n < 8; ++n)
#pragma unroll
      for (int r = 0; r < 4; ++r) {
        int row = q0 + u * 16 + lg * 4 + r;
        int col = h * HD + n * 16 + lr;
        O[(size_t)row * D + col] = __float2bfloat16(accO[u][n][r] * rs[r]);
      }
  }
}

extern "C" void kernel_launch(void* const* d_in, const int* in_sizes, int n_in,
                              void* d_out, int out_size, void* d_ws, size_t ws_size,
                              hipStream_t stream) {
  const float* x    = (const float*)d_in[0];
  const float* fcos = (const float*)d_in[1];
  const float* fsin = (const float*)d_in[2];
  const float* wq   = (const float*)d_in[3];
  const float* wk   = (const float*)d_in[4];
  const float* wv   = (const float*)d_in[5];
  const float* wo   = (const float*)d_in[6];
  float* out = (float*)d_out;

  const int S = 2048, D = 4096;
  const size_t MB = 1024 * 1024;
  char* ws = (char*)d_ws;
  bf16* xb = (bf16*)(ws);            // 16 MB
  bf16* wT = (bf16*)(ws + 16 * MB);  // 32 MB slot, stream-serialized
  bf16* Qb = (bf16*)(ws + 48 * MB);  // 16 MB
  bf16* Kb = (bf16*)(ws + 64 * MB);  // 16 MB
  bf16* Vt = (bf16*)(ws + 80 * MB);  // 16 MB  [h][d][s]
  bf16* AO = (bf16*)(ws);            // reuse xb slot after QKV GEMMs

  int n = S * D;
  castx_kernel<<<n / (256 * 8), 256, 0, stream>>>(x, xb, n);

  tw_kernel<<<4096, 256, 0, stream>>>(wq, wT);
  gemm3<1><<<256, 512, 0, stream>>>(xb, wT, Qb, S, D, D, fcos, fsin);  // Q + RoPE + scale
  tw_kernel<<<4096, 256, 0, stream>>>(wk, wT);
  gemm3<2><<<256, 512, 0, stream>>>(xb, wT, Kb, S, D, D, fcos, fsin);  // K + RoPE
  tw_kernel<<<4096, 256, 0, stream>>>(wv, wT);
  gemm3<3><<<256, 512, 0, stream>>>(xb, wT, Vt, S, D, D, nullptr, nullptr);  // V transposed

  attn_fwd<<<dim3(8, 32), 512, 0, stream>>>(Qb, Kb, Vt, AO);

  tw_kernel<<<4096, 256, 0, stream>>>(wo, wT);
  gemm3<4><<<256, 512, 0, stream>>>(AO, wT, out, S, D, D, nullptr, nullptr);
}

// Round 7
// 452.123 us; speedup vs baseline: 1.6881x; 1.6881x over previous
//
#include <hip/hip_runtime.h>
#include <hip/hip_bf16.h>

typedef __hip_bfloat16 bf16;
typedef __attribute__((ext_vector_type(8))) short short8;
typedef __attribute__((ext_vector_type(4))) short short4v;
typedef __attribute__((ext_vector_type(4))) float f32x4;

#define MFMA16(a, b, c) __builtin_amdgcn_mfma_f32_16x16x32_bf16((a), (b), (c), 0, 0, 0)

static __device__ __forceinline__ void gload_lds16(const bf16* g, bf16* l) {
  __builtin_amdgcn_global_load_lds((const __attribute__((address_space(1))) unsigned int*)g,
                                   (__attribute__((address_space(3))) unsigned int*)l,
                                   16, 0, 0);
}

// ---------------- cast x: fp32 -> bf16 ----------------
__global__ __launch_bounds__(256) void castx_kernel(const float* __restrict__ x,
                                                    bf16* __restrict__ xb, int n) {
  int i = (blockIdx.x * 256 + threadIdx.x) * 8;
  if (i >= n) return;
  float4 v0 = *(const float4*)(x + i);
  float4 v1 = *(const float4*)(x + i + 4);
  bf16 tmp[8];
  tmp[0] = __float2bfloat16(v0.x); tmp[1] = __float2bfloat16(v0.y);
  tmp[2] = __float2bfloat16(v0.z); tmp[3] = __float2bfloat16(v0.w);
  tmp[4] = __float2bfloat16(v1.x); tmp[5] = __float2bfloat16(v1.y);
  tmp[6] = __float2bfloat16(v1.z); tmp[7] = __float2bfloat16(v1.w);
  *(short8*)(xb + i) = *(short8*)tmp;
}

// ---------------- transpose+cast weight: W[K][N] fp32 -> WT[N][K] bf16 ----------------
__global__ __launch_bounds__(256) void tw_kernel(const float* __restrict__ W,
                                                 bf16* __restrict__ WT) {
  __shared__ bf16 tile[64][65];
  int b = blockIdx.x;
  int tk = (b >> 6) * 64;
  int tn = (b & 63) * 64;
  int t = threadIdx.x;
  int c = t & 63, r0 = t >> 6;
#pragma unroll
  for (int i = 0; i < 16; ++i) {
    int r = i * 4 + r0;
    tile[c][r] = __float2bfloat16(W[(size_t)(tk + r) * 4096 + tn + c]);
  }
  __syncthreads();
#pragma unroll
  for (int i = 0; i < 16; ++i) {
    int r = i * 4 + r0;
    WT[(size_t)(tn + r) * 4096 + tk + c] = tile[r][c];
  }
}

// ---------------- GEMM v4: 8-phase-style schedule, C = A*Bt^T, fused epilogues ----------
// EPI: 1 = RoPE+scale (Q), 2 = RoPE (K), 3 = transposed store Vt[col][row], 4 = fp32 store.
// BM=128 BN=256 BK=64, 512 thr = 8 waves (2m x 4n), wave tile 64x64.
// Triple-buffered LDS (3 x 48KB); K-tile kt+2 staged spread over kt's 4 quadrant-phases;
// counted vmcnt(6) once per K-tile (drains exactly next tile's 6 loads; 0 only at tail).
// Full 3-bit XOR swizzle (stage source granule ^= row&7, read granule ^= lr&7).
// Per phase: {ds_reads + 2 stages -> barrier -> setprio(1) -> 8 MFMA -> setprio(0) -> barrier}.
template <int EPI>
__global__ __launch_bounds__(512) void gemm4(const bf16* __restrict__ A,
                                             const bf16* __restrict__ Bt,
                                             void* __restrict__ Cv,
                                             int M, int N, int K,
                                             const float* __restrict__ fcos,
                                             const float* __restrict__ fsin) {
  __shared__ bf16 LDS[3][384 * 64];  // per buf: A[128][64] then B[256][64]
  const int NB = N >> 8;
  int g = blockIdx.x;
  int nwg = (M >> 7) * NB;                    // 256 for our shapes (mult of 8)
  int wid = (g & 7) * (nwg >> 3) + (g >> 3);  // XCD-chunked swizzle
  int bm = wid / NB, bn = wid % NB;
  int t = threadIdx.x, lane = t & 63, w = t >> 6;
  int wm = w >> 2, wn = w & 3;
  int lr = lane & 15, lg = lane >> 4;
  int rsw = lr & 7;
  f32x4 acc[4][4] = {};

  const bf16* Ab = A + (size_t)bm * 128 * K;
  const bf16* Bb = Bt + (size_t)bn * 256 * K;
  int srow = t >> 3;                 // 0..63 row within 64-row slab
  int sg = (t & 7) ^ (srow & 7);     // inverse-swizzled source granule
  int NK = K >> 6;

#define STA(buf, kt2, i)                                                        \
  gload_lds16(Ab + (size_t)((i) * 64 + srow) * K + (kt2) * 64 + sg * 8,         \
              LDS[buf] + ((i) * 512 + w * 64) * 8)
#define STB(buf, kt2, i)                                                        \
  gload_lds16(Bb + (size_t)((i) * 64 + srow) * K + (kt2) * 64 + sg * 8,         \
              LDS[buf] + 128 * 64 + ((i) * 512 + w * 64) * 8)
#define AFRAG(la, m, kc) \
  (*(const short8*)((la) + (wm * 64 + (m) * 16 + lr) * 64 + ((((kc) * 4 + lg) ^ rsw) << 3)))
#define BFRAG(lb, nf, kc) \
  (*(const short8*)((lb) + (wn * 64 + (nf) * 16 + lr) * 64 + ((((kc) * 4 + lg) ^ rsw) << 3)))

  // prologue: stage kt=0 and kt=1 fully
  STA(0, 0, 0); STA(0, 0, 1);
  STB(0, 0, 0); STB(0, 0, 1); STB(0, 0, 2); STB(0, 0, 3);
  STA(1, 1, 0); STA(1, 1, 1);
  STB(1, 1, 0); STB(1, 1, 1); STB(1, 1, 2); STB(1, 1, 3);
  asm volatile("s_waitcnt vmcnt(6)" ::: "memory");  // kt=0 complete
  __builtin_amdgcn_s_barrier();

  int cur = 0;
  for (int kt = 0; kt < NK; ++kt) {
    const bf16* la = LDS[cur];
    const bf16* lb = la + 128 * 64;
    int nb2 = cur + 2; if (nb2 >= 3) nb2 -= 3;
    bool pf = (kt + 2) < NK;
    short8 a0[2][2], a1[2][2], b0[2][2], b1[2][2];

    // ---- phase 0: read a0,b0; stage A-slabs of kt+2; MFMA quadrant (m0,n0) ----
#pragma unroll
    for (int i = 0; i < 2; ++i)
#pragma unroll
      for (int kc = 0; kc < 2; ++kc) {
        a0[i][kc] = AFRAG(la, i, kc);
        b0[i][kc] = BFRAG(lb, i, kc);
      }
    if (pf) { STA(nb2, kt + 2, 0); STA(nb2, kt + 2, 1); }
    __builtin_amdgcn_s_barrier();
    __builtin_amdgcn_s_setprio(1);
#pragma unroll
    for (int i = 0; i < 2; ++i)
#pragma unroll
      for (int j = 0; j < 2; ++j)
#pragma unroll
        for (int kc = 0; kc < 2; ++kc)
          acc[i][j] = MFMA16(a0[i][kc], b0[j][kc], acc[i][j]);
    __builtin_amdgcn_s_setprio(0);
    __builtin_amdgcn_s_barrier();

    // ---- phase 1: read b1; stage B-slabs 0,1; MFMA quadrant (m0,n1) ----
#pragma unroll
    for (int j = 0; j < 2; ++j)
#pragma unroll
      for (int kc = 0; kc < 2; ++kc)
        b1[j][kc] = BFRAG(lb, 2 + j, kc);
    if (pf) { STB(nb2, kt + 2, 0); STB(nb2, kt + 2, 1); }
    __builtin_amdgcn_s_barrier();
    __builtin_amdgcn_s_setprio(1);
#pragma unroll
    for (int i = 0; i < 2; ++i)
#pragma unroll
      for (int j = 0; j < 2; ++j)
#pragma unroll
        for (int kc = 0; kc < 2; ++kc)
          acc[i][2 + j] = MFMA16(a0[i][kc], b1[j][kc], acc[i][2 + j]);
    __builtin_amdgcn_s_setprio(0);
    __builtin_amdgcn_s_barrier();

    // ---- phase 2: read a1; stage B-slabs 2,3; MFMA quadrant (m1,n0) ----
#pragma unroll
    for (int i = 0; i < 2; ++i)
#pragma unroll
      for (int kc = 0; kc < 2; ++kc)
        a1[i][kc] = AFRAG(la, 2 + i, kc);
    if (pf) { STB(nb2, kt + 2, 2); STB(nb2, kt + 2, 3); }
    __builtin_amdgcn_s_barrier();
    __builtin_amdgcn_s_setprio(1);
#pragma unroll
    for (int i = 0; i < 2; ++i)
#pragma unroll
      for (int j = 0; j < 2; ++j)
#pragma unroll
        for (int kc = 0; kc < 2; ++kc)
          acc[2 + i][j] = MFMA16(a1[i][kc], b0[j][kc], acc[2 + i][j]);
    __builtin_amdgcn_s_setprio(0);
    __builtin_amdgcn_s_barrier();

    // ---- phase 3: MFMA quadrant (m1,n1); counted vmcnt for next tile ----
    __builtin_amdgcn_s_setprio(1);
#pragma unroll
    for (int i = 0; i < 2; ++i)
#pragma unroll
      for (int j = 0; j < 2; ++j)
#pragma unroll
        for (int kc = 0; kc < 2; ++kc)
          acc[2 + i][2 + j] = MFMA16(a1[i][kc], b1[j][kc], acc[2 + i][2 + j]);
    __builtin_amdgcn_s_setprio(0);
    if (pf)
      asm volatile("s_waitcnt vmcnt(6)" ::: "memory");  // drain S(kt+1) only
    else
      asm volatile("s_waitcnt vmcnt(0)" ::: "memory");  // tail
    __builtin_amdgcn_s_barrier();

    cur = (cur + 1 == 3) ? 0 : cur + 1;
  }
#undef STA
#undef STB
#undef AFRAG
#undef BFRAG

#pragma unroll
  for (int m = 0; m < 4; ++m)
#pragma unroll
    for (int nf = 0; nf < 4; ++nf) {
      int col = bn * 256 + wn * 64 + nf * 16 + lr;
      int row0 = bm * 128 + wm * 64 + m * 16 + lg * 4;
      if constexpr (EPI == 1 || EPI == 2) {
        const float qs = (EPI == 1) ? 0.08838834764831845f : 1.0f;
        int ip = (col >> 1) & 63;
        float sgn = (col & 1) ? 1.0f : -1.0f;
#pragma unroll
        for (int r = 0; r < 4; ++r) {
          int row = row0 + r;
          float mine = acc[m][nf][r];
          float oth = __shfl_xor(mine, 1);
          float cv = fcos[row * 64 + ip];
          float sv = fsin[row * 64 + ip];
          float v = (mine * cv + sgn * oth * sv) * qs;
          ((bf16*)Cv)[(size_t)row * N + col] = __float2bfloat16(v);
        }
      } else if constexpr (EPI == 3) {
        bf16 tmp[4];
#pragma unroll
        for (int r = 0; r < 4; ++r) tmp[r] = __float2bfloat16(acc[m][nf][r]);
        *(short4v*)((bf16*)Cv + (size_t)col * M + row0) = *(short4v*)tmp;
      } else {
#pragma unroll
        for (int r = 0; r < 4; ++r) {
          int row = row0 + r;
          ((float*)Cv)[(size_t)row * N + col] = acc[m][nf][r];
        }
      }
    }
}

// ---------------- Flash attention v3 (unchanged from r5) ----------------
__global__ __launch_bounds__(512, 2) void attn_fwd(const bf16* __restrict__ Q,
                                                   const bf16* __restrict__ K,
                                                   const bf16* __restrict__ Vt,
                                                   bf16* __restrict__ O) {
  __shared__ bf16 Kbuf[2][64 * 128];
  __shared__ bf16 Vbuf[2][128 * 64];
  __shared__ char Ps_all[8][2][2048];
  const int S = 2048, D = 4096, HD = 128, NT = 32;
  int g = blockIdx.y * 8 + blockIdx.x;
  int wid = (g & 7) * 32 + (g >> 3);
  int h = wid >> 3, qb = wid & 7;
  int tid = threadIdx.x, lane = tid & 63, w = tid >> 6;
  int lr = lane & 15, lg = lane >> 4;
  int q0 = qb * 256 + w * 32;
  int swz = (lr & 7) << 4;

  const bf16* Kh = K + h * HD;
  const bf16* Vh = Vt + (size_t)h * HD * S;

  short8 aq[2][4];
#pragma unroll
  for (int u = 0; u < 2; ++u)
#pragma unroll
    for (int c = 0; c < 4; ++c)
      aq[u][c] = *(const short8*)(Q + (size_t)(q0 + u * 16 + lr) * D + h * HD + c * 32 + lg * 8);

  int kr = lane >> 4, ksl = lane & 15;
  int vr = lane >> 3, vsl = lane & 7;

  f32x4 accO[2][8] = {};
  float lsum[2] = {0.f, 0.f};

#define STAGE(b, ttile)                                                            \
  do {                                                                             \
    int kv0_ = (ttile) * 64;                                                       \
    _Pragma("unroll") for (int ii = 0; ii < 2; ++ii) {                             \
      int row = w * 8 + ii * 4 + kr;                                               \
      gload_lds16(Kh + (size_t)(kv0_ + row) * D + ((ksl ^ (row & 7)) << 3),        \
                  &Kbuf[b][(w * 8 + ii * 4) * 128]);                               \
    }                                                                              \
    _Pragma("unroll") for (int ii = 0; ii < 2; ++ii) {                             \
      int row = w * 16 + ii * 8 + vr;                                              \
      gload_lds16(Vh + (size_t)row * S + kv0_ + ((vsl ^ (row & 7)) << 3),          \
                  &Vbuf[b][(w * 16 + ii * 8) * 64]);                               \
    }                                                                              \
  } while (0)

  int cur = 0;
  STAGE(0, 0);
  for (int tt = 0; tt < NT; ++tt) {
    if (tt + 1 < NT) {
      STAGE(cur ^ 1, tt + 1);
      asm volatile("s_waitcnt vmcnt(4)" ::: "memory");
    } else {
      asm volatile("s_waitcnt vmcnt(0)" ::: "memory");
    }
    __builtin_amdgcn_s_barrier();
    const bf16* Kb_ = Kbuf[cur];
    const bf16* Vb_ = Vbuf[cur];

    f32x4 sf[2][4] = {};
#pragma unroll
    for (int j = 0; j < 4; ++j)
#pragma unroll
      for (int c = 0; c < 4; ++c) {
        short8 kf = *(const short8*)(Kb_ + (j * 16 + lr) * 128 +
                                     (((c * 4 + lg) ^ (lr & 7)) << 3));
        sf[0][j] = MFMA16(kf, aq[0][c], sf[0][j]);
        sf[1][j] = MFMA16(kf, aq[1][c], sf[1][j]);
      }
#pragma unroll
    for (int u = 0; u < 2; ++u) {
      char* Ps = Ps_all[w][u];
#pragma unroll
      for (int j = 0; j < 4; ++j) {
        float p0 = __expf(sf[u][j][0]);
        float p1 = __expf(sf[u][j][1]);
        float p2 = __expf(sf[u][j][2]);
        float p3 = __expf(sf[u][j][3]);
        lsum[u] += (p0 + p1) + (p2 + p3);
        bf16 pk[4] = {__float2bfloat16(p0), __float2bfloat16(p1),
                      __float2bfloat16(p2), __float2bfloat16(p3)};
        *(short4v*)(Ps + lr * 128 + ((j * 32 + lg * 8) ^ swz)) = *(short4v*)pk;
      }
    }
#pragma unroll
    for (int t2 = 0; t2 < 2; ++t2) {
      short8 pa0 = *(const short8*)(Ps_all[w][0] + lr * 128 + ((t2 * 64 + lg * 16) ^ swz));
      short8 pa1 = *(const short8*)(Ps_all[w][1] + lr * 128 + ((t2 * 64 + lg * 16) ^ swz));
#pragma unroll
      for (int n = 0; n < 8; ++n) {
        short8 bv = *(const short8*)(Vb_ + (n * 16 + lr) * 64 +
                                     (((t2 * 4 + lg) ^ (lr & 7)) << 3));
        accO[0][n] = MFMA16(pa0, bv, accO[0][n]);
        accO[1][n] = MFMA16(pa1, bv, accO[1][n]);
      }
    }
    __builtin_amdgcn_s_barrier();
    cur ^= 1;
  }
#undef STAGE

#pragma unroll
  for (int u = 0; u < 2; ++u) {
    float ls = lsum[u];
    ls += __shfl_xor(ls, 16);
    ls += __shfl_xor(ls, 32);
    float rs[4];
#pragma unroll
    for (int r = 0; r < 4; ++r)
      rs[r] = 1.f / __shfl(ls, lg * 4 + r);
#pragma unroll
    for (int n = 0; n < 8; ++n)
#pragma unroll
      for (int r = 0; r < 4; ++r) {
        int row = q0 + u * 16 + lg * 4 + r;
        int col = h * HD + n * 16 + lr;
        O[(size_t)row * D + col] = __float2bfloat16(accO[u][n][r] * rs[r]);
      }
  }
}

extern "C" void kernel_launch(void* const* d_in, const int* in_sizes, int n_in,
                              void* d_out, int out_size, void* d_ws, size_t ws_size,
                              hipStream_t stream) {
  const float* x    = (const float*)d_in[0];
  const float* fcos = (const float*)d_in[1];
  const float* fsin = (const float*)d_in[2];
  const float* wq   = (const float*)d_in[3];
  const float* wk   = (const float*)d_in[4];
  const float* wv   = (const float*)d_in[5];
  const float* wo   = (const float*)d_in[6];
  float* out = (float*)d_out;

  const int S = 2048, D = 4096;
  const size_t MB = 1024 * 1024;
  char* ws = (char*)d_ws;
  bf16* xb = (bf16*)(ws);            // 16 MB
  bf16* wT = (bf16*)(ws + 16 * MB);  // 32 MB slot, stream-serialized
  bf16* Qb = (bf16*)(ws + 48 * MB);  // 16 MB
  bf16* Kb = (bf16*)(ws + 64 * MB);  // 16 MB
  bf16* Vt = (bf16*)(ws + 80 * MB);  // 16 MB  [h][d][s]
  bf16* AO = (bf16*)(ws);            // reuse xb slot after QKV GEMMs

  int n = S * D;
  castx_kernel<<<n / (256 * 8), 256, 0, stream>>>(x, xb, n);

  tw_kernel<<<4096, 256, 0, stream>>>(wq, wT);
  gemm4<1><<<256, 512, 0, stream>>>(xb, wT, Qb, S, D, D, fcos, fsin);  // Q + RoPE + scale
  tw_kernel<<<4096, 256, 0, stream>>>(wk, wT);
  gemm4<2><<<256, 512, 0, stream>>>(xb, wT, Kb, S, D, D, fcos, fsin);  // K + RoPE
  tw_kernel<<<4096, 256, 0, stream>>>(wv, wT);
  gemm4<3><<<256, 512, 0, stream>>>(xb, wT, Vt, S, D, D, nullptr, nullptr);  // V transposed

  attn_fwd<<<dim3(8, 32), 512, 0, stream>>>(Qb, Kb, Vt, AO);

  tw_kernel<<<4096, 256, 0, stream>>>(wo, wT);
  gemm4<4><<<256, 512, 0, stream>>>(AO, wT, out, S, D, D, nullptr, nullptr);
}

// Round 8
// 428.270 us; speedup vs baseline: 1.7821x; 1.0557x over previous
//
#include <hip/hip_runtime.h>
#include <hip/hip_bf16.h>

typedef __hip_bfloat16 bf16;
typedef __attribute__((ext_vector_type(8))) short short8;
typedef __attribute__((ext_vector_type(4))) short short4v;
typedef __attribute__((ext_vector_type(4))) float f32x4;

#define MFMA16(a, b, c) __builtin_amdgcn_mfma_f32_16x16x32_bf16((a), (b), (c), 0, 0, 0)

static __device__ __forceinline__ void gload_lds16(const bf16* g, bf16* l) {
  __builtin_amdgcn_global_load_lds((const __attribute__((address_space(1))) unsigned int*)g,
                                   (__attribute__((address_space(3))) unsigned int*)l,
                                   16, 0, 0);
}

// ---------------- cast x: fp32 -> bf16 ----------------
__global__ __launch_bounds__(256) void castx_kernel(const float* __restrict__ x,
                                                    bf16* __restrict__ xb, int n) {
  int i = (blockIdx.x * 256 + threadIdx.x) * 8;
  if (i >= n) return;
  float4 v0 = *(const float4*)(x + i);
  float4 v1 = *(const float4*)(x + i + 4);
  bf16 tmp[8];
  tmp[0] = __float2bfloat16(v0.x); tmp[1] = __float2bfloat16(v0.y);
  tmp[2] = __float2bfloat16(v0.z); tmp[3] = __float2bfloat16(v0.w);
  tmp[4] = __float2bfloat16(v1.x); tmp[5] = __float2bfloat16(v1.y);
  tmp[6] = __float2bfloat16(v1.z); tmp[7] = __float2bfloat16(v1.w);
  *(short8*)(xb + i) = *(short8*)tmp;
}

// ---------------- transpose+cast weight: W[K][N] fp32 -> WT[N][K] bf16 ----------------
__global__ __launch_bounds__(256) void tw_kernel(const float* __restrict__ W,
                                                 bf16* __restrict__ WT) {
  __shared__ bf16 tile[64][65];
  int b = blockIdx.x;
  int tk = (b >> 6) * 64;
  int tn = (b & 63) * 64;
  int t = threadIdx.x;
  int c = t & 63, r0 = t >> 6;
#pragma unroll
  for (int i = 0; i < 16; ++i) {
    int r = i * 4 + r0;
    tile[c][r] = __float2bfloat16(W[(size_t)(tk + r) * 4096 + tn + c]);
  }
  __syncthreads();
#pragma unroll
  for (int i = 0; i < 16; ++i) {
    int r = i * 4 + r0;
    WT[(size_t)(tn + r) * 4096 + tk + c] = tile[r][c];
  }
}

// ---------------- Fused Q+K GEMM: C = xb[2048][4096] * wT2[8192][4096]^T ----------------
// BM=256 BN=256 BK=32, 512 thr = 8 waves (2m x 4n), wave tile 128x64 (M_rep=8, N_rep=4).
// Triple-buffered LDS 3x32KB = 96KB; tile kt+2 staged spread over kt's 4 phases;
// counted vmcnt(4) once per K-tile. Swizzle: read granule ^= (lr>>1)&3, stage source
// granule = (t&3) ^ ((t>>3)&3) (verified inverse pair; max 2-way bank alias = free).
// Per phase: {ds_reads ; 1 stage ; barrier ; setprio 8xMFMA ; barrier}.
// Epilogue: n-section 0 -> Q (RoPE + 1/sqrt(hd) scale), 1 -> K (RoPE).
__global__ __launch_bounds__(512) void gemmQK(const bf16* __restrict__ A,
                                              const bf16* __restrict__ Bt,
                                              bf16* __restrict__ Qb,
                                              bf16* __restrict__ Kb,
                                              const float* __restrict__ fcos,
                                              const float* __restrict__ fsin) {
  __shared__ bf16 LDS[3 * 16384];  // per buf: A[256][32] then B[256][32]
  const int K = 4096, NK = 128;
  int g = blockIdx.x;
  int wid = (g & 7) * 32 + (g >> 3);  // XCD-chunked: one XCD owns one bm-panel
  int bm = wid >> 5, bn = wid & 31;
  int t = threadIdx.x, lane = t & 63, w = t >> 6;
  int wm = w >> 2, wn = w & 3;        // wave tile: rows wm*128, cols wn*64
  int lr = lane & 15, lg = lane >> 4;
  int rg = lg ^ ((lr >> 1) & 3);      // read granule swizzle (lane-only)
  f32x4 acc[8][4] = {};

  const bf16* Ab = A + (size_t)bm * 256 * K;
  const bf16* Bb = Bt + (size_t)bn * 256 * K;
  int srow = t >> 2;                  // 0..127 row within 128-row slab
  int sg = (t & 3) ^ ((t >> 3) & 3);  // inverse-swizzled source granule

#define STG(buf, kt2, mat, i)                                                     \
  gload_lds16(((mat) ? Bb : Ab) + (size_t)((i) * 128 + srow) * K + (kt2) * 32 + sg * 8, \
              LDS + (buf) * 16384 + (mat) * 8192 + (i) * 4096 + w * 512)
#define AFR(la, mi) \
  (*(const short8*)(LDS + (la) + (wm * 128 + (mi) * 16 + lr) * 32 + (rg << 3)))
#define BFR(la, nf) \
  (*(const short8*)(LDS + (la) + 8192 + (wn * 64 + (nf) * 16 + lr) * 32 + (rg << 3)))

  // prologue: stage tiles 0 and 1
  STG(0, 0, 0, 0); STG(0, 0, 0, 1); STG(0, 0, 1, 0); STG(0, 0, 1, 1);
  STG(1, 1, 0, 0); STG(1, 1, 0, 1); STG(1, 1, 1, 0); STG(1, 1, 1, 1);
  asm volatile("s_waitcnt vmcnt(4)" ::: "memory");  // tile 0 complete
  __builtin_amdgcn_s_barrier();

  int cur = 0;
  for (int kt = 0; kt < NK; ++kt) {
    int la = cur * 16384;
    int stb = (cur + 2 >= 3) ? cur - 1 : cur + 2;
    bool pf = (kt + 2) < NK;
    short8 b[4], a0, a1;

    // ---- phase 0: read all B + a0,a1; stage A-slab0; MFMA rows 0-1 ----
    b[0] = BFR(la, 0); b[1] = BFR(la, 1); b[2] = BFR(la, 2); b[3] = BFR(la, 3);
    a0 = AFR(la, 0); a1 = AFR(la, 1);
    if (pf) STG(stb, kt + 2, 0, 0);
    __builtin_amdgcn_s_barrier();
    __builtin_amdgcn_s_setprio(1);
#pragma unroll
    for (int nf = 0; nf < 4; ++nf) {
      acc[0][nf] = MFMA16(a0, b[nf], acc[0][nf]);
      acc[1][nf] = MFMA16(a1, b[nf], acc[1][nf]);
    }
    __builtin_amdgcn_s_setprio(0);
    __builtin_amdgcn_s_barrier();

    // ---- phase 1: a2,a3; stage A-slab1; MFMA rows 2-3 ----
    a0 = AFR(la, 2); a1 = AFR(la, 3);
    if (pf) STG(stb, kt + 2, 0, 1);
    __builtin_amdgcn_s_barrier();
    __builtin_amdgcn_s_setprio(1);
#pragma unroll
    for (int nf = 0; nf < 4; ++nf) {
      acc[2][nf] = MFMA16(a0, b[nf], acc[2][nf]);
      acc[3][nf] = MFMA16(a1, b[nf], acc[3][nf]);
    }
    __builtin_amdgcn_s_setprio(0);
    __builtin_amdgcn_s_barrier();

    // ---- phase 2: a4,a5; stage B-slab0; MFMA rows 4-5 ----
    a0 = AFR(la, 4); a1 = AFR(la, 5);
    if (pf) STG(stb, kt + 2, 1, 0);
    __builtin_amdgcn_s_barrier();
    __builtin_amdgcn_s_setprio(1);
#pragma unroll
    for (int nf = 0; nf < 4; ++nf) {
      acc[4][nf] = MFMA16(a0, b[nf], acc[4][nf]);
      acc[5][nf] = MFMA16(a1, b[nf], acc[5][nf]);
    }
    __builtin_amdgcn_s_setprio(0);
    __builtin_amdgcn_s_barrier();

    // ---- phase 3: a6,a7; stage B-slab1; MFMA rows 6-7; counted vmcnt ----
    a0 = AFR(la, 6); a1 = AFR(la, 7);
    if (pf) STG(stb, kt + 2, 1, 1);
    __builtin_amdgcn_s_barrier();
    __builtin_amdgcn_s_setprio(1);
#pragma unroll
    for (int nf = 0; nf < 4; ++nf) {
      acc[6][nf] = MFMA16(a0, b[nf], acc[6][nf]);
      acc[7][nf] = MFMA16(a1, b[nf], acc[7][nf]);
    }
    __builtin_amdgcn_s_setprio(0);
    if (pf)
      asm volatile("s_waitcnt vmcnt(4)" ::: "memory");  // next tile's 4 done
    else
      asm volatile("s_waitcnt vmcnt(0)" ::: "memory");
    __builtin_amdgcn_s_barrier();

    cur = (cur + 1 == 3) ? 0 : cur + 1;
  }
#undef STG
#undef AFR
#undef BFR

  // ---- epilogue: RoPE; section 0 -> Q (scaled), 1 -> K ----
  int sect = bn >> 4, bnl = bn & 15;
  bf16* Cb = sect ? Kb : Qb;
  const float qs = sect ? 1.0f : 0.08838834764831845f;
#pragma unroll
  for (int mi = 0; mi < 8; ++mi)
#pragma unroll
    for (int nf = 0; nf < 4; ++nf) {
      int col = bnl * 256 + wn * 64 + nf * 16 + lr;
      int row0 = bm * 256 + wm * 128 + mi * 16 + lg * 4;
      int ip = (col >> 1) & 63;
      float sgn = (col & 1) ? 1.0f : -1.0f;
#pragma unroll
      for (int r = 0; r < 4; ++r) {
        int row = row0 + r;
        float mine = acc[mi][nf][r];
        float oth = __shfl_xor(mine, 1);
        float cv = fcos[row * 64 + ip];
        float sv = fsin[row * 64 + ip];
        float v = (mine * cv + sgn * oth * sv) * qs;
        Cb[(size_t)row * 4096 + col] = __float2bfloat16(v);
      }
    }
}

// ---------------- GEMM v4 (unchanged from r7; used for V and wo) ----------------
// EPI: 3 = transposed store Vt[col][row], 4 = fp32 store.
template <int EPI>
__global__ __launch_bounds__(512) void gemm4(const bf16* __restrict__ A,
                                             const bf16* __restrict__ Bt,
                                             void* __restrict__ Cv,
                                             int M, int N, int K) {
  __shared__ bf16 LDS[3][384 * 64];
  const int NB = N >> 8;
  int g = blockIdx.x;
  int nwg = (M >> 7) * NB;
  int wid = (g & 7) * (nwg >> 3) + (g >> 3);
  int bm = wid / NB, bn = wid % NB;
  int t = threadIdx.x, lane = t & 63, w = t >> 6;
  int wm = w >> 2, wn = w & 3;
  int lr = lane & 15, lg = lane >> 4;
  int rsw = lr & 7;
  f32x4 acc[4][4] = {};

  const bf16* Ab = A + (size_t)bm * 128 * K;
  const bf16* Bb = Bt + (size_t)bn * 256 * K;
  int srow = t >> 3;
  int sg = (t & 7) ^ (srow & 7);
  int NK = K >> 6;

#define STA(buf, kt2, i)                                                        \
  gload_lds16(Ab + (size_t)((i) * 64 + srow) * K + (kt2) * 64 + sg * 8,         \
              LDS[buf] + ((i) * 512 + w * 64) * 8)
#define STB(buf, kt2, i)                                                        \
  gload_lds16(Bb + (size_t)((i) * 64 + srow) * K + (kt2) * 64 + sg * 8,         \
              LDS[buf] + 128 * 64 + ((i) * 512 + w * 64) * 8)
#define AFRAG(la, m, kc) \
  (*(const short8*)((la) + (wm * 64 + (m) * 16 + lr) * 64 + ((((kc) * 4 + lg) ^ rsw) << 3)))
#define BFRAG(lb, nf, kc) \
  (*(const short8*)((lb) + (wn * 64 + (nf) * 16 + lr) * 64 + ((((kc) * 4 + lg) ^ rsw) << 3)))

  STA(0, 0, 0); STA(0, 0, 1);
  STB(0, 0, 0); STB(0, 0, 1); STB(0, 0, 2); STB(0, 0, 3);
  STA(1, 1, 0); STA(1, 1, 1);
  STB(1, 1, 0); STB(1, 1, 1); STB(1, 1, 2); STB(1, 1, 3);
  asm volatile("s_waitcnt vmcnt(6)" ::: "memory");
  __builtin_amdgcn_s_barrier();

  int cur = 0;
  for (int kt = 0; kt < NK; ++kt) {
    const bf16* la = LDS[cur];
    const bf16* lb = la + 128 * 64;
    int nb2 = cur + 2; if (nb2 >= 3) nb2 -= 3;
    bool pf = (kt + 2) < NK;
    short8 a0[2][2], a1[2][2], b0[2][2], b1[2][2];

#pragma unroll
    for (int i = 0; i < 2; ++i)
#pragma unroll
      for (int kc = 0; kc < 2; ++kc) {
        a0[i][kc] = AFRAG(la, i, kc);
        b0[i][kc] = BFRAG(lb, i, kc);
      }
    if (pf) { STA(nb2, kt + 2, 0); STA(nb2, kt + 2, 1); }
    __builtin_amdgcn_s_barrier();
    __builtin_amdgcn_s_setprio(1);
#pragma unroll
    for (int i = 0; i < 2; ++i)
#pragma unroll
      for (int j = 0; j < 2; ++j)
#pragma unroll
        for (int kc = 0; kc < 2; ++kc)
          acc[i][j] = MFMA16(a0[i][kc], b0[j][kc], acc[i][j]);
    __builtin_amdgcn_s_setprio(0);
    __builtin_amdgcn_s_barrier();

#pragma unroll
    for (int j = 0; j < 2; ++j)
#pragma unroll
      for (int kc = 0; kc < 2; ++kc)
        b1[j][kc] = BFRAG(lb, 2 + j, kc);
    if (pf) { STB(nb2, kt + 2, 0); STB(nb2, kt + 2, 1); }
    __builtin_amdgcn_s_barrier();
    __builtin_amdgcn_s_setprio(1);
#pragma unroll
    for (int i = 0; i < 2; ++i)
#pragma unroll
      for (int j = 0; j < 2; ++j)
#pragma unroll
        for (int kc = 0; kc < 2; ++kc)
          acc[i][2 + j] = MFMA16(a0[i][kc], b1[j][kc], acc[i][2 + j]);
    __builtin_amdgcn_s_setprio(0);
    __builtin_amdgcn_s_barrier();

#pragma unroll
    for (int i = 0; i < 2; ++i)
#pragma unroll
      for (int kc = 0; kc < 2; ++kc)
        a1[i][kc] = AFRAG(la, 2 + i, kc);
    if (pf) { STB(nb2, kt + 2, 2); STB(nb2, kt + 2, 3); }
    __builtin_amdgcn_s_barrier();
    __builtin_amdgcn_s_setprio(1);
#pragma unroll
    for (int i = 0; i < 2; ++i)
#pragma unroll
      for (int j = 0; j < 2; ++j)
#pragma unroll
        for (int kc = 0; kc < 2; ++kc)
          acc[2 + i][j] = MFMA16(a1[i][kc], b0[j][kc], acc[2 + i][j]);
    __builtin_amdgcn_s_setprio(0);
    __builtin_amdgcn_s_barrier();

    __builtin_amdgcn_s_setprio(1);
#pragma unroll
    for (int i = 0; i < 2; ++i)
#pragma unroll
      for (int j = 0; j < 2; ++j)
#pragma unroll
        for (int kc = 0; kc < 2; ++kc)
          acc[2 + i][2 + j] = MFMA16(a1[i][kc], b1[j][kc], acc[2 + i][2 + j]);
    __builtin_amdgcn_s_setprio(0);
    if (pf)
      asm volatile("s_waitcnt vmcnt(6)" ::: "memory");
    else
      asm volatile("s_waitcnt vmcnt(0)" ::: "memory");
    __builtin_amdgcn_s_barrier();

    cur = (cur + 1 == 3) ? 0 : cur + 1;
  }
#undef STA
#undef STB
#undef AFRAG
#undef BFRAG

#pragma unroll
  for (int m = 0; m < 4; ++m)
#pragma unroll
    for (int nf = 0; nf < 4; ++nf) {
      int col = bn * 256 + wn * 64 + nf * 16 + lr;
      int row0 = bm * 128 + wm * 64 + m * 16 + lg * 4;
      if constexpr (EPI == 3) {
        bf16 tmp[4];
#pragma unroll
        for (int r = 0; r < 4; ++r) tmp[r] = __float2bfloat16(acc[m][nf][r]);
        *(short4v*)((bf16*)Cv + (size_t)col * M + row0) = *(short4v*)tmp;
      } else {
#pragma unroll
        for (int r = 0; r < 4; ++r) {
          int row = row0 + r;
          ((float*)Cv)[(size_t)row * N + col] = acc[m][nf][r];
        }
      }
    }
}

// ---------------- Flash attention v3 (unchanged from r5) ----------------
__global__ __launch_bounds__(512, 2) void attn_fwd(const bf16* __restrict__ Q,
                                                   const bf16* __restrict__ K,
                                                   const bf16* __restrict__ Vt,
                                                   bf16* __restrict__ O) {
  __shared__ bf16 Kbuf[2][64 * 128];
  __shared__ bf16 Vbuf[2][128 * 64];
  __shared__ char Ps_all[8][2][2048];
  const int S = 2048, D = 4096, HD = 128, NT = 32;
  int g = blockIdx.y * 8 + blockIdx.x;
  int wid = (g & 7) * 32 + (g >> 3);
  int h = wid >> 3, qb = wid & 7;
  int tid = threadIdx.x, lane = tid & 63, w = tid >> 6;
  int lr = lane & 15, lg = lane >> 4;
  int q0 = qb * 256 + w * 32;
  int swz = (lr & 7) << 4;

  const bf16* Kh = K + h * HD;
  const bf16* Vh = Vt + (size_t)h * HD * S;

  short8 aq[2][4];
#pragma unroll
  for (int u = 0; u < 2; ++u)
#pragma unroll
    for (int c = 0; c < 4; ++c)
      aq[u][c] = *(const short8*)(Q + (size_t)(q0 + u * 16 + lr) * D + h * HD + c * 32 + lg * 8);

  int kr = lane >> 4, ksl = lane & 15;
  int vr = lane >> 3, vsl = lane & 7;

  f32x4 accO[2][8] = {};
  float lsum[2] = {0.f, 0.f};

#define STAGE(b, ttile)                                                            \
  do {                                                                             \
    int kv0_ = (ttile) * 64;                                                       \
    _Pragma("unroll") for (int ii = 0; ii < 2; ++ii) {                             \
      int row = w * 8 + ii * 4 + kr;                                               \
      gload_lds16(Kh + (size_t)(kv0_ + row) * D + ((ksl ^ (row & 7)) << 3),        \
                  &Kbuf[b][(w * 8 + ii * 4) * 128]);                               \
    }                                                                              \
    _Pragma("unroll") for (int ii = 0; ii < 2; ++ii) {                             \
      int row = w * 16 + ii * 8 + vr;                                              \
      gload_lds16(Vh + (size_t)row * S + kv0_ + ((vsl ^ (row & 7)) << 3),          \
                  &Vbuf[b][(w * 16 + ii * 8) * 64]);                               \
    }                                                                              \
  } while (0)

  int cur = 0;
  STAGE(0, 0);
  for (int tt = 0; tt < NT; ++tt) {
    if (tt + 1 < NT) {
      STAGE(cur ^ 1, tt + 1);
      asm volatile("s_waitcnt vmcnt(4)" ::: "memory");
    } else {
      asm volatile("s_waitcnt vmcnt(0)" ::: "memory");
    }
    __builtin_amdgcn_s_barrier();
    const bf16* Kb_ = Kbuf[cur];
    const bf16* Vb_ = Vbuf[cur];

    f32x4 sf[2][4] = {};
#pragma unroll
    for (int j = 0; j < 4; ++j)
#pragma unroll
      for (int c = 0; c < 4; ++c) {
        short8 kf = *(const short8*)(Kb_ + (j * 16 + lr) * 128 +
                                     (((c * 4 + lg) ^ (lr & 7)) << 3));
        sf[0][j] = MFMA16(kf, aq[0][c], sf[0][j]);
        sf[1][j] = MFMA16(kf, aq[1][c], sf[1][j]);
      }
#pragma unroll
    for (int u = 0; u < 2; ++u) {
      char* Ps = Ps_all[w][u];
#pragma unroll
      for (int j = 0; j < 4; ++j) {
        float p0 = __expf(sf[u][j][0]);
        float p1 = __expf(sf[u][j][1]);
        float p2 = __expf(sf[u][j][2]);
        float p3 = __expf(sf[u][j][3]);
        lsum[u] += (p0 + p1) + (p2 + p3);
        bf16 pk[4] = {__float2bfloat16(p0), __float2bfloat16(p1),
                      __float2bfloat16(p2), __float2bfloat16(p3)};
        *(short4v*)(Ps + lr * 128 + ((j * 32 + lg * 8) ^ swz)) = *(short4v*)pk;
      }
    }
#pragma unroll
    for (int t2 = 0; t2 < 2; ++t2) {
      short8 pa0 = *(const short8*)(Ps_all[w][0] + lr * 128 + ((t2 * 64 + lg * 16) ^ swz));
      short8 pa1 = *(const short8*)(Ps_all[w][1] + lr * 128 + ((t2 * 64 + lg * 16) ^ swz));
#pragma unroll
      for (int n = 0; n < 8; ++n) {
        short8 bv = *(const short8*)(Vb_ + (n * 16 + lr) * 64 +
                                     (((t2 * 4 + lg) ^ (lr & 7)) << 3));
        accO[0][n] = MFMA16(pa0, bv, accO[0][n]);
        accO[1][n] = MFMA16(pa1, bv, accO[1][n]);
      }
    }
    __builtin_amdgcn_s_barrier();
    cur ^= 1;
  }
#undef STAGE

#pragma unroll
  for (int u = 0; u < 2; ++u) {
    float ls = lsum[u];
    ls += __shfl_xor(ls, 16);
    ls += __shfl_xor(ls, 32);
    float rs[4];
#pragma unroll
    for (int r = 0; r < 4; ++r)
      rs[r] = 1.f / __shfl(ls, lg * 4 + r);
#pragma unroll
    for (int n = 0; n < 8; ++n)
#pragma unroll
      for (int r = 0; r < 4; ++r) {
        int row = q0 + u * 16 + lg * 4 + r;
        int col = h * HD + n * 16 + lr;
        O[(size_t)row * D + col] = __float2bfloat16(accO[u][n][r] * rs[r]);
      }
  }
}

extern "C" void kernel_launch(void* const* d_in, const int* in_sizes, int n_in,
                              void* d_out, int out_size, void* d_ws, size_t ws_size,
                              hipStream_t stream) {
  const float* x    = (const float*)d_in[0];
  const float* fcos = (const float*)d_in[1];
  const float* fsin = (const float*)d_in[2];
  const float* wq   = (const float*)d_in[3];
  const float* wk   = (const float*)d_in[4];
  const float* wv   = (const float*)d_in[5];
  const float* wo   = (const float*)d_in[6];
  float* out = (float*)d_out;

  const int S = 2048, D = 4096;
  const size_t MB = 1024 * 1024;
  char* ws = (char*)d_ws;
  bf16* xb  = (bf16*)(ws);            // [0,16)  x bf16; later AO
  bf16* wT2 = (bf16*)(ws + 16 * MB);  // [16,80) wq-T | wk-T contiguous (QK fused);
                                      //         later [16,48) = wv-T, then wo-T
  bf16* Vt  = (bf16*)(ws + 48 * MB);  // [48,80) Vt[h][d][s] (after wk-T dead)
  bf16* Qb  = (bf16*)(ws + 80 * MB);  // [80,96)
  bf16* Kb  = (bf16*)(ws + 96 * MB);  // [96,112)
  bf16* AO  = (bf16*)(ws);            // reuse xb slot after QKV GEMMs

  int n = S * D;
  castx_kernel<<<n / (256 * 8), 256, 0, stream>>>(x, xb, n);

  // fused Q+K: transpose wq, wk into contiguous wT2[8192][4096]
  tw_kernel<<<4096, 256, 0, stream>>>(wq, wT2);
  tw_kernel<<<4096, 256, 0, stream>>>(wk, wT2 + (size_t)4096 * 4096);
  gemmQK<<<256, 512, 0, stream>>>(xb, wT2, Qb, Kb, fcos, fsin);

  // V: old gemm4 with transposed store (wk-T region now dead -> Vt there)
  tw_kernel<<<4096, 256, 0, stream>>>(wv, wT2);  // wv-T at [16,48)
  gemm4<3><<<256, 512, 0, stream>>>(xb, wT2, Vt, S, D, D);

  attn_fwd<<<dim3(8, 32), 512, 0, stream>>>(Qb, Kb, Vt, AO);

  tw_kernel<<<4096, 256, 0, stream>>>(wo, wT2);  // wo-T at [16,48)
  gemm4<4><<<256, 512, 0, stream>>>(AO, wT2, out, S, D, D);
}